// Round 2
// baseline (597.152 us; speedup 1.0000x reference)
//
#include <hip/hip_runtime.h>

typedef unsigned short u16;
using bf16x8 = __attribute__((ext_vector_type(8))) short;
using f32x4  = __attribute__((ext_vector_type(4))) float;

static __device__ __forceinline__ u16 f2b(float f) {
  unsigned int x = __builtin_bit_cast(unsigned int, f);
  unsigned int r = (x + 0x7fffu + ((x >> 16) & 1u)) >> 16;
  return (u16)r;
}
static __device__ __forceinline__ float fin(float x) { return (x != x) ? 0.f : x; }
static __device__ __forceinline__ float expclamp(float x) {
  return __expf(fminf(fmaxf(x, -80.f), 80.f));
}

#define SCALE 0.04419417382415922f  // 1/sqrt(512)

#define MFMA16(a, b, c) __builtin_amdgcn_mfma_f32_16x16x32_bf16((a), (b), (c), 0, 0, 0)

// global->LDS direct copy, 16B per lane. LDS dest = wave-uniform base + lane*16.
static __device__ __forceinline__ void glds16(const u16* g, u16* l) {
  __builtin_amdgcn_global_load_lds(
      (const __attribute__((address_space(1))) unsigned int*)(unsigned long long)(const void*)g,
      (__attribute__((address_space(3))) unsigned int*)(unsigned int)(unsigned long long)(void*)l,
      16, 0, 0);
}

// Memory plan (ws budget: exactly 33,554,432 B):
//   ws:    K bf16 [8][2048][512] @0;  Vt bf16 [8][512][2048] (V TRANSPOSED) @16.78MB
//   d_out: per fp32-row r (4096 B): [0,1024) Q bf16 row stash (stride 2048 u16),
//          [1024,1032) denom partial sums (2 floats, slots 256/257) for column i=r%2048,
//          [2048,4096) read output (fp32). copy_in (LAST) overwrites [0,2048).

// ---------------- K1: QKV projection, MFMA GEMM ----------------
__global__ __launch_bounds__(256) void qkv_mfma(
    const float* __restrict__ X,
    const float* __restrict__ Wq, const float* __restrict__ bq,
    const float* __restrict__ Wk, const float* __restrict__ bk,
    const float* __restrict__ Wv, const float* __restrict__ bv,
    u16* __restrict__ outq, u16* __restrict__ Kw, u16* __restrict__ Vt) {
  __shared__ __align__(16) u16 SM[16384];  // As[128][64] | Bs[128][64]; reused as Tr[128][128]
  u16* As = SM;
  u16* Bs = SM + 8192;
  const int z = blockIdx.z;
  const float* W = (z == 0) ? Wq : ((z == 1) ? Wk : Wv);
  const float* bias = (z == 0) ? bq : ((z == 1) ? bk : bv);
  const int row0 = blockIdx.x * 128;
  const int col0 = blockIdx.y * 128;
  const int tid = threadIdx.x, lane = tid & 63, w = tid >> 6;
  const int lrow = lane & 15, lg = lane >> 4;
  const int qm = w >> 1, qn = w & 1;
  const int srow = tid >> 1, sh = tid & 1;

  const f32x4 Z4 = {0.f, 0.f, 0.f, 0.f};
  f32x4 acc[4][4];
#pragma unroll
  for (int m = 0; m < 4; ++m)
#pragma unroll
    for (int n = 0; n < 4; ++n) acc[m][n] = Z4;

  const float* Xr = X + (size_t)(row0 + srow) * 512;
  const float* Wr = W + (size_t)(col0 + srow) * 512;

  for (int ks = 0; ks < 8; ++ks) {
    const int k0 = ks * 64;
    __syncthreads();
#pragma unroll
    for (int s4 = 0; s4 < 4; ++s4) {
      const int slot = sh * 4 + s4;
      const int ds = ((slot ^ (srow & 7)) << 3);
      {
        float4 f0 = *(const float4*)(Xr + k0 + slot * 8);
        float4 f1 = *(const float4*)(Xr + k0 + slot * 8 + 4);
        uint4 pk;
        pk.x = f2b(f0.x) | ((unsigned)f2b(f0.y) << 16);
        pk.y = f2b(f0.z) | ((unsigned)f2b(f0.w) << 16);
        pk.z = f2b(f1.x) | ((unsigned)f2b(f1.y) << 16);
        pk.w = f2b(f1.z) | ((unsigned)f2b(f1.w) << 16);
        *(uint4*)&As[srow * 64 + ds] = pk;
      }
      {
        float4 f0 = *(const float4*)(Wr + k0 + slot * 8);
        float4 f1 = *(const float4*)(Wr + k0 + slot * 8 + 4);
        uint4 pk;
        pk.x = f2b(f0.x) | ((unsigned)f2b(f0.y) << 16);
        pk.y = f2b(f0.z) | ((unsigned)f2b(f0.w) << 16);
        pk.z = f2b(f1.x) | ((unsigned)f2b(f1.y) << 16);
        pk.w = f2b(f1.z) | ((unsigned)f2b(f1.w) << 16);
        *(uint4*)&Bs[srow * 64 + ds] = pk;
      }
    }
    __syncthreads();
#pragma unroll
    for (int cs = 0; cs < 2; ++cs) {
      bf16x8 af[4], bfr[4];
#pragma unroll
      for (int mf = 0; mf < 4; ++mf) {
        const int r = qm * 64 + mf * 16 + lrow;
        af[mf] = *(const bf16x8*)&As[r * 64 + (((cs * 4 + lg) ^ (r & 7)) << 3)];
      }
#pragma unroll
      for (int nf = 0; nf < 4; ++nf) {
        const int r = qn * 64 + nf * 16 + lrow;
        bfr[nf] = *(const bf16x8*)&Bs[r * 64 + (((cs * 4 + lg) ^ (r & 7)) << 3)];
      }
#pragma unroll
      for (int mf = 0; mf < 4; ++mf)
#pragma unroll
        for (int nf = 0; nf < 4; ++nf)
          acc[mf][nf] = MFMA16(af[mf], bfr[nf], acc[mf][nf]);
    }
  }

  // D layout: col = lane&15, row = (lane>>4)*4 + reg.
  if (z < 2) {
    u16* O = (z == 0) ? outq : Kw;
    const int ldo = (z == 0) ? 2048 : 512;
#pragma unroll
    for (int mf = 0; mf < 4; ++mf)
#pragma unroll
      for (int nf = 0; nf < 4; ++nf) {
        const int C = col0 + qn * 64 + nf * 16 + lrow;
        const float bb = bias[C];
#pragma unroll
        for (int r = 0; r < 4; ++r) {
          const int R = row0 + qm * 64 + mf * 16 + lg * 4 + r;
          O[(size_t)R * ldo + C] = f2b(fin(acc[mf][nf][r] + bb));
        }
      }
  } else {
    // V: transpose tile through LDS, store Vt[b][v][t] coalesced.
    __syncthreads();
    u16* Tr = SM;  // [128][128]
#pragma unroll
    for (int mf = 0; mf < 4; ++mf)
#pragma unroll
      for (int nf = 0; nf < 4; ++nf) {
        const int vl = qn * 64 + nf * 16 + lrow;
        const float bb = bias[col0 + vl];
#pragma unroll
        for (int r = 0; r < 4; ++r) {
          const int tl = qm * 64 + mf * 16 + lg * 4 + r;
          Tr[vl * 128 + tl] = f2b(fin(acc[mf][nf][r] + bb));
        }
      }
    __syncthreads();
    const int vl = tid >> 1, part = tid & 1;
    const int bI = row0 >> 11;
    u16* dst = Vt + (size_t)(bI * 512 + col0 + vl) * 2048 + (row0 & 2047) + part * 64;
    const u16* sp = &Tr[vl * 128 + part * 64];
#pragma unroll
    for (int q = 0; q < 8; ++q)
      *(uint4*)(dst + q * 8) = *(const uint4*)(sp + q * 8);
  }
}

// ---------------- K2: column denominator partials via MFMA ----------------
// Block (x, b): pr = x>>1 pairs i-tiles (pr, 63-pr); h = x&1 takes j-tiles
// jt ≡ {4h..4h+3} (mod 8).  Writes RAW partial sum to slot 256+h; read_mfma
// combines 1/(s0+s1).  Grid 512 -> 2 blocks/CU, 2 waves/SIMD.
__global__ __launch_bounds__(256) void denom_mfma(
    const u16* __restrict__ Qs, const u16* __restrict__ Kw, float* __restrict__ rdn) {
  __shared__ float red[4][32];
  const int b = blockIdx.y;
  const int x = blockIdx.x;          // 0..63
  const int pr = x >> 1, h = x & 1;
  const int tid = threadIdx.x, lane = tid & 63, w = tid >> 6;
  const int lrow = lane & 15, lg = lane >> 4;
  for (int pass = 0; pass < 2; ++pass) {
    const int it = pass ? (63 - pr) : pr;
    const int i0 = it * 32;
    bf16x8 Kf[2][16];
#pragma unroll
    for (int f = 0; f < 2; ++f) {
      const u16* kr = Kw + (size_t)(b * 2048 + i0 + f * 16 + lrow) * 512;
#pragma unroll
      for (int cs = 0; cs < 16; ++cs) Kf[f][cs] = *(const bf16x8*)(kr + cs * 32 + lg * 8);
    }
    float ps[2][4];
#pragma unroll
    for (int f = 0; f < 2; ++f)
#pragma unroll
      for (int r = 0; r < 4; ++r) ps[f][r] = 0.f;
    for (int jt = 2 * it + 4 * h + w; jt < 128; jt += 8) {
      const int j0 = jt * 16;
      const u16* qr = Qs + (size_t)(b * 2048 + j0 + lrow) * 2048;
      bf16x8 Qf[16];
#pragma unroll
      for (int cs = 0; cs < 16; ++cs) Qf[cs] = *(const bf16x8*)(qr + cs * 32 + lg * 8);
#pragma unroll
      for (int f = 0; f < 2; ++f) {
        f32x4 s = {0.f, 0.f, 0.f, 0.f};
#pragma unroll
        for (int cs = 0; cs < 16; ++cs) s = MFMA16(Kf[f][cs], Qf[cs], s);
        const int j = j0 + lrow;
#pragma unroll
        for (int r = 0; r < 4; ++r) {
          const int i = i0 + f * 16 + lg * 4 + r;
          if (j >= i) ps[f][r] += expclamp(s[r] * SCALE);
        }
      }
    }
#pragma unroll
    for (int f = 0; f < 2; ++f)
#pragma unroll
      for (int r = 0; r < 4; ++r) {
        float v = ps[f][r];
        v += __shfl_xor(v, 1); v += __shfl_xor(v, 2);
        v += __shfl_xor(v, 4); v += __shfl_xor(v, 8);
        if (lrow == 0) red[w][f * 16 + lg * 4 + r] = v;
      }
    __syncthreads();
    if (tid < 32) {
      const float d = red[0][tid] + red[1][tid] + red[2][tid] + red[3][tid];
      rdn[(size_t)(b * 2048 + i0 + tid) * 1024 + 256 + h] = d;
    }
    __syncthreads();
  }
}

// ---------------- K3: fused causal read, flash-style MFMA ----------------
// Grid (64, 8).  Block mapping: q = bx>>1, s = bx&1; jt = s ? 31-q : q; vh = s.
// Adjacent block pairs (2q, 2q+1) carry jts {q, 31-q} -> constant 66-window
// load per co-resident pair.  4 waves x 16 j; 32-i windows; K double-buffered
// via glds (swizzled source); V fragments read DIRECT from global (L1/L2-hot);
// PV covers only v-half vh (16 vt, 64 accum VGPRs).  LDS 70.7 KiB -> 2 blk/CU.
__global__ __launch_bounds__(256) void read_mfma(
    const u16* __restrict__ Qs, const u16* __restrict__ Kw, const u16* __restrict__ Vt,
    const float* __restrict__ rdn, float* __restrict__ outf) {
  __shared__ __align__(16) u16 KB[2][16384];  // [32 i][512 c], slot^=(row&7)
  __shared__ __align__(16) u16 PB[4][640];    // per-wave P[16 j][32 i], stride 40 u16
  const int bx = blockIdx.x, b = blockIdx.y;
  const int q = bx >> 1, s = bx & 1;
  const int jt = s ? (31 - q) : q;
  const int vh = s;
  const int j0 = jt * 64;
  const int tid = threadIdx.x, lane = tid & 63, w = tid >> 6;
  const int lrow = lane & 15, lg = lane >> 4;
  const int NW = 2 * (jt + 1);

  bf16x8 Qf[16];
  {
    const u16* qr = Qs + (size_t)(b * 2048 + j0 + w * 16 + lrow) * 2048;
#pragma unroll
    for (int cs = 0; cs < 16; ++cs) Qf[cs] = *(const bf16x8*)(qr + cs * 32 + lg * 8);
  }
  const f32x4 Z4 = {0.f, 0.f, 0.f, 0.f};
  f32x4 O[16];
#pragma unroll
  for (int vt = 0; vt < 16; ++vt) O[vt] = Z4;
  u16* pw = &PB[w][0];

  const size_t kbase = (size_t)b * 2048 * 512;
  const size_t vbase = (size_t)b * 512 * 2048;
  auto stage = [&](int buf, int i0) {
#pragma unroll
    for (int p = 0; p < 8; ++p) {
      const int row = p * 4 + w;
      glds16(Kw + kbase + (size_t)(i0 + row) * 512 + ((lane ^ (row & 7)) << 3),
             &KB[buf][row * 512]);
    }
  };

  stage(0, 0);
  for (int win = 0; win < NW; ++win) {
    const int cur = win & 1;
    const int i0 = win * 32;
    // denom partial-sum loads (issued early; combined after QK)
    const float2 ra = *(const float2*)&rdn[(size_t)(b * 2048 + i0 + lrow) * 1024 + 256];
    const float2 rb = *(const float2*)&rdn[(size_t)(b * 2048 + i0 + 16 + lrow) * 1024 + 256];
    if (win + 1 < NW) {
      stage(cur ^ 1, i0 + 32);
      // drain current window's 8 K-glds; keep next 8 + 2 rdenom loads in flight
      asm volatile("s_waitcnt vmcnt(10)" ::: "memory");
    } else {
      asm volatile("s_waitcnt vmcnt(2)" ::: "memory");
    }
    __builtin_amdgcn_s_barrier();

    const u16* kb = &KB[cur][0];
    f32x4 s0 = Z4, s1 = Z4;
#pragma unroll
    for (int cs = 0; cs < 16; ++cs) {
      const int sl = cs * 4 + lg;
      bf16x8 k0 = *(const bf16x8*)(kb + lrow * 512 + ((sl ^ (lrow & 7)) << 3));
      bf16x8 k1 = *(const bf16x8*)(kb + (16 + lrow) * 512 + ((sl ^ (lrow & 7)) << 3));
      s0 = MFMA16(Qf[cs], k0, s0);
      s1 = MFMA16(Qf[cs], k1, s1);
    }
    const float rd0 = 1.0f / fmaxf(ra.x + ra.y, 1e-30f);
    const float rd1 = 1.0f / fmaxf(rb.x + rb.y, 1e-30f);
    const int jb = j0 + w * 16 + lg * 4;
#pragma unroll
    for (int r = 0; r < 4; ++r) {
      const int jj = jb + r;
      const float e0 = (i0 + lrow <= jj) ? expclamp(s0[r] * SCALE) * rd0 : 0.f;
      const float e1 = (i0 + 16 + lrow <= jj) ? expclamp(s1[r] * SCALE) * rd1 : 0.f;
      pw[(lg * 4 + r) * 40 + lrow] = f2b(e0);
      pw[(lg * 4 + r) * 40 + 16 + lrow] = f2b(e1);
    }
    asm volatile("s_waitcnt lgkmcnt(0)" ::: "memory");
    const bf16x8 pa = *(const bf16x8*)(pw + lrow * 40 + lg * 8);
#pragma unroll
    for (int t = 0; t < 16; ++t) {
      const int vloc = (vh * 16 + t) * 16 + lrow;
      const bf16x8 vf = *(const bf16x8*)(Vt + vbase + (size_t)vloc * 2048 + i0 + lg * 8);
      O[t] = MFMA16(pa, vf, O[t]);
    }
    __builtin_amdgcn_s_barrier();  // all QK reads of buf[cur] done before restage
  }

#pragma unroll
  for (int t = 0; t < 16; ++t) {
    const int v = (vh * 16 + t) * 16 + lrow;
#pragma unroll
    for (int r = 0; r < 4; ++r) {
      const int jj = j0 + w * 16 + lg * 4 + r;
      outf[(size_t)(b * 2048 + jj) * 1024 + 512 + v] = fin(O[t][r]);
    }
  }
}

// ---------------- K4: passthrough fp32 X -> out[:,0:512] (LAST) ----------------
__global__ __launch_bounds__(256) void copy_in_kernel(
    const float* __restrict__ X, float* __restrict__ outf) {
  size_t idx = (size_t)blockIdx.x * 256 + threadIdx.x;
  size_t row = idx >> 7;
  int c = (int)(idx & 127) * 4;
  *(float4*)&outf[row * 1024 + c] = *(const float4*)&X[row * 512 + c];
}

extern "C" void kernel_launch(void* const* d_in, const int* in_sizes, int n_in,
                              void* d_out, int out_size, void* d_ws, size_t ws_size,
                              hipStream_t stream) {
  const float* X  = (const float*)d_in[0];
  const float* Wq = (const float*)d_in[1];
  const float* bq = (const float*)d_in[2];
  const float* Wk = (const float*)d_in[3];
  const float* bk = (const float*)d_in[4];
  const float* Wv = (const float*)d_in[5];
  const float* bv = (const float*)d_in[6];

  char* ws = (char*)d_ws;
  const size_t SZ = (size_t)16384 * 512 * sizeof(u16);
  u16* Kw = (u16*)(ws);
  u16* Vt = (u16*)(ws + SZ);

  qkv_mfma<<<dim3(128, 4, 3), 256, 0, stream>>>(X, Wq, bq, Wk, bk, Wv, bv,
                                                (u16*)d_out, Kw, Vt);
  denom_mfma<<<dim3(64, 8), 256, 0, stream>>>((const u16*)d_out, Kw, (float*)d_out);
  read_mfma<<<dim3(64, 8), 256, 0, stream>>>((const u16*)d_out, Kw, Vt,
                                             (const float*)d_out, (float*)d_out);
  copy_in_kernel<<<8192, 256, 0, stream>>>(X, (float*)d_out);
}

// Round 3
// 495.858 us; speedup vs baseline: 1.2043x; 1.2043x over previous
//
#include <hip/hip_runtime.h>

typedef unsigned short u16;
using bf16x8 = __attribute__((ext_vector_type(8))) short;
using f32x4  = __attribute__((ext_vector_type(4))) float;

static __device__ __forceinline__ u16 f2b(float f) {
  unsigned int x = __builtin_bit_cast(unsigned int, f);
  unsigned int r = (x + 0x7fffu + ((x >> 16) & 1u)) >> 16;
  return (u16)r;
}
static __device__ __forceinline__ float fin(float x) { return (x != x) ? 0.f : x; }
static __device__ __forceinline__ float expclamp(float x) {
  return __expf(fminf(fmaxf(x, -80.f), 80.f));
}
// packed f32->bf16 RNE convert (same rounding as f2b)
static __device__ __forceinline__ unsigned cvt2(float lo, float hi) {
  unsigned r;
  asm("v_cvt_pk_bf16_f32 %0, %1, %2" : "=v"(r) : "v"(lo), "v"(hi));
  return r;
}

#define SCALE 0.04419417382415922f  // 1/sqrt(512)
#define MFMA16(a, b, c) __builtin_amdgcn_mfma_f32_16x16x32_bf16((a), (b), (c), 0, 0, 0)

static __device__ __forceinline__ void glds16(const u16* g, u16* l) {
  __builtin_amdgcn_global_load_lds(
      (const __attribute__((address_space(1))) unsigned int*)(unsigned long long)(const void*)g,
      (__attribute__((address_space(3))) unsigned int*)(unsigned int)(unsigned long long)(void*)l,
      16, 0, 0);
}

// Memory plan (ws = 33,554,432 B exactly):
//   ws: K bf16 [8][2048][512] @0; Vt bf16 [8][512][2048] (V transposed) @16.78MB
//   d_out per fp32-row r (4096 B): [0,1024) Q bf16 stash (stride 2048 u16),
//   [1024,1028) denom f32 (column i=r%2048), [2048,4096) read output.
//   copy_in (LAST) overwrites [0,2048).

// ---------------- K1: QKV projection, MFMA GEMM ----------------
__global__ __launch_bounds__(256) void qkv_mfma(
    const float* __restrict__ X,
    const float* __restrict__ Wq, const float* __restrict__ bq,
    const float* __restrict__ Wk, const float* __restrict__ bk,
    const float* __restrict__ Wv, const float* __restrict__ bv,
    u16* __restrict__ outq, u16* __restrict__ Kw, u16* __restrict__ Vt) {
  __shared__ __align__(16) u16 SM[16384];  // As[128][64] | Bs[128][64]; reused as Tr[128][128]
  u16* As = SM;
  u16* Bs = SM + 8192;
  const int z = blockIdx.z;
  const float* W = (z == 0) ? Wq : ((z == 1) ? Wk : Wv);
  const float* bias = (z == 0) ? bq : ((z == 1) ? bk : bv);
  const int row0 = blockIdx.x * 128;
  const int col0 = blockIdx.y * 128;
  const int tid = threadIdx.x, lane = tid & 63, w = tid >> 6;
  const int lrow = lane & 15, lg = lane >> 4;
  const int qm = w >> 1, qn = w & 1;
  const int srow = tid >> 1, sh = tid & 1;

  const f32x4 Z4 = {0.f, 0.f, 0.f, 0.f};
  f32x4 acc[4][4];
#pragma unroll
  for (int m = 0; m < 4; ++m)
#pragma unroll
    for (int n = 0; n < 4; ++n) acc[m][n] = Z4;

  const float* Xr = X + (size_t)(row0 + srow) * 512;
  const float* Wr = W + (size_t)(col0 + srow) * 512;

  for (int ks = 0; ks < 8; ++ks) {
    const int k0 = ks * 64;
    __syncthreads();
#pragma unroll
    for (int s4 = 0; s4 < 4; ++s4) {
      const int slot = sh * 4 + s4;
      const int ds = ((slot ^ (srow & 7)) << 3);
      {
        float4 f0 = *(const float4*)(Xr + k0 + slot * 8);
        float4 f1 = *(const float4*)(Xr + k0 + slot * 8 + 4);
        uint4 pk;
        pk.x = cvt2(f0.x, f0.y); pk.y = cvt2(f0.z, f0.w);
        pk.z = cvt2(f1.x, f1.y); pk.w = cvt2(f1.z, f1.w);
        *(uint4*)&As[srow * 64 + ds] = pk;
      }
      {
        float4 f0 = *(const float4*)(Wr + k0 + slot * 8);
        float4 f1 = *(const float4*)(Wr + k0 + slot * 8 + 4);
        uint4 pk;
        pk.x = cvt2(f0.x, f0.y); pk.y = cvt2(f0.z, f0.w);
        pk.z = cvt2(f1.x, f1.y); pk.w = cvt2(f1.z, f1.w);
        *(uint4*)&Bs[srow * 64 + ds] = pk;
      }
    }
    __syncthreads();
#pragma unroll
    for (int cs = 0; cs < 2; ++cs) {
      bf16x8 af[4], bfr[4];
#pragma unroll
      for (int mf = 0; mf < 4; ++mf) {
        const int r = qm * 64 + mf * 16 + lrow;
        af[mf] = *(const bf16x8*)&As[r * 64 + (((cs * 4 + lg) ^ (r & 7)) << 3)];
      }
#pragma unroll
      for (int nf = 0; nf < 4; ++nf) {
        const int r = qn * 64 + nf * 16 + lrow;
        bfr[nf] = *(const bf16x8*)&Bs[r * 64 + (((cs * 4 + lg) ^ (r & 7)) << 3)];
      }
#pragma unroll
      for (int mf = 0; mf < 4; ++mf)
#pragma unroll
        for (int nf = 0; nf < 4; ++nf)
          acc[mf][nf] = MFMA16(af[mf], bfr[nf], acc[mf][nf]);
    }
  }

  if (z < 2) {
    u16* O = (z == 0) ? outq : Kw;
    const int ldo = (z == 0) ? 2048 : 512;
#pragma unroll
    for (int mf = 0; mf < 4; ++mf)
#pragma unroll
      for (int nf = 0; nf < 4; ++nf) {
        const int C = col0 + qn * 64 + nf * 16 + lrow;
        const float bb = bias[C];
#pragma unroll
        for (int r = 0; r < 4; ++r) {
          const int R = row0 + qm * 64 + mf * 16 + lg * 4 + r;
          O[(size_t)R * ldo + C] = f2b(fin(acc[mf][nf][r] + bb));
        }
      }
  } else {
    __syncthreads();
    u16* Tr = SM;  // [128][128]
#pragma unroll
    for (int mf = 0; mf < 4; ++mf)
#pragma unroll
      for (int nf = 0; nf < 4; ++nf) {
        const int vl = qn * 64 + nf * 16 + lrow;
        const float bb = bias[col0 + vl];
#pragma unroll
        for (int r = 0; r < 4; ++r) {
          const int tl = qm * 64 + mf * 16 + lg * 4 + r;
          Tr[vl * 128 + tl] = f2b(fin(acc[mf][nf][r] + bb));
        }
      }
    __syncthreads();
    const int vl = tid >> 1, part = tid & 1;
    const int bI = row0 >> 11;
    u16* dst = Vt + (size_t)(bI * 512 + col0 + vl) * 2048 + (row0 & 2047) + part * 64;
    const u16* sp = &Tr[vl * 128 + part * 64];
#pragma unroll
    for (int q = 0; q < 8; ++q)
      *(uint4*)(dst + q * 8) = *(const uint4*)(sp + q * 8);
  }
}

// ---------------- K2: column denominators ----------------
// 256 equal blocks: pair (px, 63-px) of 32-i tiles, done sequentially.
// 8 waves = (ih in {0,1}) x (jq in {0..3}). K rows in regs (A operand), Q staged
// via glds double-buffer (shared by all waves). Column sums accumulate in regs
// over the j-sweep; cross-jq combine via tiny LDS; direct store (no atomics).
__global__ __launch_bounds__(512, 2) void denom_mfma(
    const u16* __restrict__ Qs, const u16* __restrict__ Kw, float* __restrict__ rdn) {
  __shared__ __align__(16) u16 QB[2][32768];  // [64 j][512 c] swizzled
  __shared__ float red[2][4][16];
  const int px = blockIdx.x, b = blockIdx.y;
  const int tid = threadIdx.x, lane = tid & 63, w = tid >> 6;
  const int lrow = lane & 15, lg = lane >> 4;
  const int ih = w >> 2, jq = w & 3;
  const size_t kbase = (size_t)b * 2048 * 512;
  const f32x4 Z4 = {0.f, 0.f, 0.f, 0.f};

  for (int half = 0; half < 2; ++half) {
    const int it = half ? (63 - px) : px;
    const int i0 = it * 32;
    bf16x8 Kf[16];
    const u16* kr = Kw + kbase + (size_t)(i0 + ih * 16 + lrow) * 512;
#pragma unroll
    for (int cs = 0; cs < 16; ++cs) Kf[cs] = *(const bf16x8*)(kr + cs * 32 + lg * 8);
    float dacc[4] = {0.f, 0.f, 0.f, 0.f};
    const int jstart = i0 & ~63;
    const int NW = (2048 - jstart) >> 6;
#pragma unroll
    for (int p = 0; p < 8; ++p) {
      const int row = p * 8 + w;
      glds16(Qs + (size_t)(b * 2048 + jstart + row) * 2048 + ((lane ^ (row & 7)) << 3),
             &QB[0][row * 512]);
    }
    for (int win = 0; win < NW; ++win) {
      const int cur = win & 1;
      const int j0w = jstart + win * 64;
      if (win + 1 < NW) {
#pragma unroll
        for (int p = 0; p < 8; ++p) {
          const int row = p * 8 + w;
          glds16(Qs + (size_t)(b * 2048 + j0w + 64 + row) * 2048 + ((lane ^ (row & 7)) << 3),
                 &QB[cur ^ 1][row * 512]);
        }
        asm volatile("s_waitcnt vmcnt(8)" ::: "memory");
      } else {
        asm volatile("s_waitcnt vmcnt(0)" ::: "memory");
      }
      __builtin_amdgcn_s_barrier();
      const u16* qb = &QB[cur][0];
      const int qrow = jq * 16 + lrow;
      f32x4 sA = Z4, sB = Z4;
#pragma unroll
      for (int cs = 0; cs < 8; ++cs) {
        bf16x8 q0 = *(const bf16x8*)(qb + qrow * 512 + (((cs * 4 + lg) ^ (qrow & 7)) << 3));
        bf16x8 q1 = *(const bf16x8*)(qb + qrow * 512 + ((((cs + 8) * 4 + lg) ^ (qrow & 7)) << 3));
        sA = MFMA16(Kf[cs], q0, sA);
        sB = MFMA16(Kf[cs + 8], q1, sB);
      }
      // D: col=lane&15 -> j_local; row=lg*4+r -> i_local
      const int jG = j0w + jq * 16 + lrow;
      const int ib = i0 + ih * 16 + lg * 4;
#pragma unroll
      for (int r = 0; r < 4; ++r) {
        float e = (jG >= ib + r) ? expclamp((sA[r] + sB[r]) * SCALE) : 0.f;
        e += __shfl_xor(e, 1); e += __shfl_xor(e, 2);
        e += __shfl_xor(e, 4); e += __shfl_xor(e, 8);
        dacc[r] += e;  // sum over this wave's 16 j; i fixed per (lg,r)
      }
      asm volatile("s_waitcnt lgkmcnt(0)" ::: "memory");
      __builtin_amdgcn_s_barrier();  // QB[cur] reads done before restage
    }
    if (lrow == 0) {
#pragma unroll
      for (int r = 0; r < 4; ++r) red[ih][jq][lg * 4 + r] = dacc[r];
    }
    __syncthreads();
    if (tid < 32) {
      const int ihh = tid >> 4, il = tid & 15;
      const float d = red[ihh][0][il] + red[ihh][1][il] + red[ihh][2][il] + red[ihh][3][il];
      rdn[(size_t)(b * 2048 + i0 + ihh * 16 + il) * 1024 + 256] = d;
    }
    __syncthreads();
  }
}

// ---------------- K3: fused causal read ----------------
// 256 equal blocks: pair (px, 63-px) of 32-j tiles sequentially (33 windows of
// 64-i total). 8 waves: QK role (jh, iq), PV role (jh, vq) -- no redundancy.
// Q in regs; K via glds dbuf + counted vmcnt; V prefetched to regs at window
// top (latency hidden under QK); P through LDS [32][64+8].
__global__ __launch_bounds__(512, 2) void read_mfma(
    const u16* __restrict__ Qs, const u16* __restrict__ Kw, const u16* __restrict__ Vt,
    const float* __restrict__ rdn, float* __restrict__ outf) {
  __shared__ __align__(16) u16 KB[2][32768];  // [64 i][512 c] swizzled
  __shared__ __align__(16) u16 PB[32 * 72];   // P[32 j][64 i], stride 72
  const int px = blockIdx.x, b = blockIdx.y;
  const int tid = threadIdx.x, lane = tid & 63, w = tid >> 6;
  const int lrow = lane & 15, lg = lane >> 4;
  const int jh = w >> 2, q4 = w & 3;  // q4 = i-quarter (QK) = v-quarter (PV)
  const size_t kbase = (size_t)b * 2048 * 512;
  const size_t vbase = (size_t)b * 512 * 2048;
  const f32x4 Z4 = {0.f, 0.f, 0.f, 0.f};

  for (int half = 0; half < 2; ++half) {
    const int jt = half ? (63 - px) : px;
    const int j0 = jt * 32;
    const int NW = (jt + 2) >> 1;  // ceil((jt+1)/2) windows of 64 i

    bf16x8 Qf[16];
    const u16* qr = Qs + (size_t)(b * 2048 + j0 + jh * 16 + lrow) * 2048;
#pragma unroll
    for (int cs = 0; cs < 16; ++cs) Qf[cs] = *(const bf16x8*)(qr + cs * 32 + lg * 8);
    f32x4 O[8];
#pragma unroll
    for (int t = 0; t < 8; ++t) O[t] = Z4;

#pragma unroll
    for (int p = 0; p < 8; ++p) {  // prologue: stage window 0
      const int row = p * 8 + w;
      glds16(Kw + kbase + (size_t)row * 512 + ((lane ^ (row & 7)) << 3),
             &KB[0][row * 512]);
    }

    for (int win = 0; win < NW; ++win) {
      const int cur = win & 1;
      const int i0 = win * 64;
      bf16x8 Vp[16];  // V prefetch: consumed after QK+exp (T14)
#pragma unroll
      for (int t = 0; t < 8; ++t)
#pragma unroll
        for (int is = 0; is < 2; ++is)
          Vp[t * 2 + is] = *(const bf16x8*)(
              Vt + vbase + (size_t)(q4 * 128 + t * 16 + lrow) * 2048 + i0 + is * 32 + lg * 8);
      const float dsum = rdn[(size_t)(b * 2048 + i0 + q4 * 16 + lrow) * 1024 + 256];
      if (win + 1 < NW) {
        const int ni = i0 + 64;
#pragma unroll
        for (int p = 0; p < 8; ++p) {
          const int row = p * 8 + w;
          glds16(Kw + kbase + (size_t)(ni + row) * 512 + ((lane ^ (row & 7)) << 3),
                 &KB[cur ^ 1][row * 512]);
        }
        // drain this window's 8 K-glds; keep 16 Vp + 1 rdn + 8 next-K in flight
        asm volatile("s_waitcnt vmcnt(25)" ::: "memory");
      } else {
        asm volatile("s_waitcnt vmcnt(17)" ::: "memory");
      }
      __builtin_amdgcn_s_barrier();

      const u16* kb = &KB[cur][0];
      const int krow = q4 * 16 + lrow;
      f32x4 sA = Z4, sB = Z4;
#pragma unroll
      for (int cs = 0; cs < 8; ++cs) {
        bf16x8 k0 = *(const bf16x8*)(kb + krow * 512 + (((cs * 4 + lg) ^ (krow & 7)) << 3));
        bf16x8 k1 = *(const bf16x8*)(kb + krow * 512 + ((((cs + 8) * 4 + lg) ^ (krow & 7)) << 3));
        sA = MFMA16(Qf[cs], k0, sA);
        sB = MFMA16(Qf[cs + 8], k1, sB);
      }
      // drain Vp + rdn (keep next-K in flight)
      if (win + 1 < NW) asm volatile("s_waitcnt vmcnt(8)" ::: "memory");
      else              asm volatile("s_waitcnt vmcnt(0)" ::: "memory");
      const float rd = 1.0f / fmaxf(dsum, 1e-30f);
      const int iG = i0 + q4 * 16 + lrow;
      const int jb = j0 + jh * 16 + lg * 4;
#pragma unroll
      for (int r = 0; r < 4; ++r) {
        const float e = (iG <= jb + r) ? expclamp((sA[r] + sB[r]) * SCALE) * rd : 0.f;
        PB[(jh * 16 + lg * 4 + r) * 72 + q4 * 16 + lrow] = f2b(e);
      }
      asm volatile("s_waitcnt lgkmcnt(0)" ::: "memory");
      __builtin_amdgcn_s_barrier();  // P ready (and all KB[cur] reads complete)

      const bf16x8 pa0 = *(const bf16x8*)&PB[(jh * 16 + lrow) * 72 + lg * 8];
      const bf16x8 pa1 = *(const bf16x8*)&PB[(jh * 16 + lrow) * 72 + 32 + lg * 8];
#pragma unroll
      for (int t = 0; t < 8; ++t) {
        O[t] = MFMA16(pa0, Vp[t * 2 + 0], O[t]);
        O[t] = MFMA16(pa1, Vp[t * 2 + 1], O[t]);
      }
    }

#pragma unroll
    for (int t = 0; t < 8; ++t) {
      const int v = q4 * 128 + t * 16 + lrow;
#pragma unroll
      for (int r = 0; r < 4; ++r) {
        const int jj = j0 + jh * 16 + lg * 4 + r;
        outf[(size_t)(b * 2048 + jj) * 1024 + 512 + v] = fin(O[t][r]);
      }
    }
    __syncthreads();  // protect KB/PB before next half restages
  }
}

// ---------------- K4: passthrough fp32 X -> out[:,0:512] (LAST) ----------------
__global__ __launch_bounds__(256) void copy_in_kernel(
    const float* __restrict__ X, float* __restrict__ outf) {
  size_t idx = (size_t)blockIdx.x * 256 + threadIdx.x;
  size_t row = idx >> 7;
  int c = (int)(idx & 127) * 4;
  *(float4*)&outf[row * 1024 + c] = *(const float4*)&X[row * 512 + c];
}

extern "C" void kernel_launch(void* const* d_in, const int* in_sizes, int n_in,
                              void* d_out, int out_size, void* d_ws, size_t ws_size,
                              hipStream_t stream) {
  const float* X  = (const float*)d_in[0];
  const float* Wq = (const float*)d_in[1];
  const float* bq = (const float*)d_in[2];
  const float* Wk = (const float*)d_in[3];
  const float* bk = (const float*)d_in[4];
  const float* Wv = (const float*)d_in[5];
  const float* bv = (const float*)d_in[6];

  char* ws = (char*)d_ws;
  const size_t SZ = (size_t)16384 * 512 * sizeof(u16);
  u16* Kw = (u16*)(ws);
  u16* Vt = (u16*)(ws + SZ);

  qkv_mfma<<<dim3(128, 4, 3), 256, 0, stream>>>(X, Wq, bq, Wk, bk, Wv, bv,
                                                (u16*)d_out, Kw, Vt);
  denom_mfma<<<dim3(32, 8), 512, 0, stream>>>((const u16*)d_out, Kw, (float*)d_out);
  read_mfma<<<dim3(32, 8), 512, 0, stream>>>((const u16*)d_out, Kw, Vt,
                                             (const float*)d_out, (float*)d_out);
  copy_in_kernel<<<8192, 256, 0, stream>>>(X, (float*)d_out);
}

// Round 4
// 452.846 us; speedup vs baseline: 1.3187x; 1.0950x over previous
//
#include <hip/hip_runtime.h>

typedef unsigned short u16;
using bf16x8 = __attribute__((ext_vector_type(8))) short;
using f32x4  = __attribute__((ext_vector_type(4))) float;

static __device__ __forceinline__ u16 f2b(float f) {
  unsigned int x = __builtin_bit_cast(unsigned int, f);
  unsigned int r = (x + 0x7fffu + ((x >> 16) & 1u)) >> 16;
  return (u16)r;
}
static __device__ __forceinline__ float fin(float x) { return (x != x) ? 0.f : x; }
static __device__ __forceinline__ float expclamp(float x) {
  return __expf(fminf(fmaxf(x, -80.f), 80.f));
}
// packed f32->bf16 RNE convert (same rounding as f2b)
static __device__ __forceinline__ unsigned cvt2(float lo, float hi) {
  unsigned r;
  asm("v_cvt_pk_bf16_f32 %0, %1, %2" : "=v"(r) : "v"(lo), "v"(hi));
  return r;
}

#define SCALE 0.04419417382415922f  // 1/sqrt(512)
#define MFMA16(a, b, c) __builtin_amdgcn_mfma_f32_16x16x32_bf16((a), (b), (c), 0, 0, 0)

static __device__ __forceinline__ void glds16(const u16* g, u16* l) {
  __builtin_amdgcn_global_load_lds(
      (const __attribute__((address_space(1))) unsigned int*)(unsigned long long)(const void*)g,
      (__attribute__((address_space(3))) unsigned int*)(unsigned int)(unsigned long long)(void*)l,
      16, 0, 0);
}

// Memory plan (ws = 33,554,432 B exactly):
//   ws: K bf16 [8][2048][512] @0; Vt bf16 [8][512][2048] (V transposed) @16.78MB
//   d_out per fp32-row r (4096 B): [0,1024) Q bf16 stash (stride 2048 u16),
//   [1024,1028) denom f32 (column i=r%2048), [2048,4096) read output.
//   copy_in (LAST) overwrites [0,2048).
//
// XCD placement (T1): dispatch round-robins blockIdx across the 8 XCDs, so we
// decode b = id&7 -> all blocks of batch b share XCD b, making K[b]+Vt[b]
// (4 MB) resp. Q[b] (2 MB) resident in that XCD's 4 MB L2.

// ---------------- K1: QKV projection, MFMA GEMM ----------------
// 1-D grid 1536 = 8 xcd x 16 row-tiles x 12 (by,z).  Each XCD owns 16 row-tiles
// of X; the 12 blocks sharing one X row-tile are slot-adjacent (L2-hot X), and
// all three W matrices (3 MB) stay L2-resident per XCD.
__global__ __launch_bounds__(256) void qkv_mfma(
    const float* __restrict__ X,
    const float* __restrict__ Wq, const float* __restrict__ bq,
    const float* __restrict__ Wk, const float* __restrict__ bk,
    const float* __restrict__ Wv, const float* __restrict__ bv,
    u16* __restrict__ outq, u16* __restrict__ Kw, u16* __restrict__ Vt) {
  __shared__ __align__(16) u16 SM[16384];  // As[128][64] | Bs[128][64]; reused as Tr[128][128]
  u16* As = SM;
  u16* Bs = SM + 8192;
  const int id = blockIdx.x;
  const int xcd = id & 7;
  const int slot = id >> 3;          // 0..191
  const int bxl = slot / 12;         // 0..15
  const int byz = slot - bxl * 12;   // 0..11
  const int z = byz >> 2;            // 0..2
  const int by = byz & 3;            // 0..3
  const int bx = (xcd << 4) + bxl;   // 0..127
  const float* W = (z == 0) ? Wq : ((z == 1) ? Wk : Wv);
  const float* bias = (z == 0) ? bq : ((z == 1) ? bk : bv);
  const int row0 = bx * 128;
  const int col0 = by * 128;
  const int tid = threadIdx.x, lane = tid & 63, w = tid >> 6;
  const int lrow = lane & 15, lg = lane >> 4;
  const int qm = w >> 1, qn = w & 1;
  const int srow = tid >> 1, sh = tid & 1;

  const f32x4 Z4 = {0.f, 0.f, 0.f, 0.f};
  f32x4 acc[4][4];
#pragma unroll
  for (int m = 0; m < 4; ++m)
#pragma unroll
    for (int n = 0; n < 4; ++n) acc[m][n] = Z4;

  const float* Xr = X + (size_t)(row0 + srow) * 512;
  const float* Wr = W + (size_t)(col0 + srow) * 512;

  for (int ks = 0; ks < 8; ++ks) {
    const int k0 = ks * 64;
    __syncthreads();
#pragma unroll
    for (int s4 = 0; s4 < 4; ++s4) {
      const int slt = sh * 4 + s4;
      const int ds = ((slt ^ (srow & 7)) << 3);
      {
        float4 f0 = *(const float4*)(Xr + k0 + slt * 8);
        float4 f1 = *(const float4*)(Xr + k0 + slt * 8 + 4);
        uint4 pk;
        pk.x = cvt2(f0.x, f0.y); pk.y = cvt2(f0.z, f0.w);
        pk.z = cvt2(f1.x, f1.y); pk.w = cvt2(f1.z, f1.w);
        *(uint4*)&As[srow * 64 + ds] = pk;
      }
      {
        float4 f0 = *(const float4*)(Wr + k0 + slt * 8);
        float4 f1 = *(const float4*)(Wr + k0 + slt * 8 + 4);
        uint4 pk;
        pk.x = cvt2(f0.x, f0.y); pk.y = cvt2(f0.z, f0.w);
        pk.z = cvt2(f1.x, f1.y); pk.w = cvt2(f1.z, f1.w);
        *(uint4*)&Bs[srow * 64 + ds] = pk;
      }
    }
    __syncthreads();
#pragma unroll
    for (int cs = 0; cs < 2; ++cs) {
      bf16x8 af[4], bfr[4];
#pragma unroll
      for (int mf = 0; mf < 4; ++mf) {
        const int r = qm * 64 + mf * 16 + lrow;
        af[mf] = *(const bf16x8*)&As[r * 64 + (((cs * 4 + lg) ^ (r & 7)) << 3)];
      }
#pragma unroll
      for (int nf = 0; nf < 4; ++nf) {
        const int r = qn * 64 + nf * 16 + lrow;
        bfr[nf] = *(const bf16x8*)&Bs[r * 64 + (((cs * 4 + lg) ^ (r & 7)) << 3)];
      }
#pragma unroll
      for (int mf = 0; mf < 4; ++mf)
#pragma unroll
        for (int nf = 0; nf < 4; ++nf)
          acc[mf][nf] = MFMA16(af[mf], bfr[nf], acc[mf][nf]);
    }
  }

  if (z < 2) {
    u16* O = (z == 0) ? outq : Kw;
    const int ldo = (z == 0) ? 2048 : 512;
#pragma unroll
    for (int mf = 0; mf < 4; ++mf)
#pragma unroll
      for (int nf = 0; nf < 4; ++nf) {
        const int C = col0 + qn * 64 + nf * 16 + lrow;
        const float bb = bias[C];
#pragma unroll
        for (int r = 0; r < 4; ++r) {
          const int R = row0 + qm * 64 + mf * 16 + lg * 4 + r;
          O[(size_t)R * ldo + C] = f2b(fin(acc[mf][nf][r] + bb));
        }
      }
  } else {
    __syncthreads();
    u16* Tr = SM;  // [128][128]
#pragma unroll
    for (int mf = 0; mf < 4; ++mf)
#pragma unroll
      for (int nf = 0; nf < 4; ++nf) {
        const int vl = qn * 64 + nf * 16 + lrow;
        const float bb = bias[col0 + vl];
#pragma unroll
        for (int r = 0; r < 4; ++r) {
          const int tl = qm * 64 + mf * 16 + lg * 4 + r;
          Tr[vl * 128 + tl] = f2b(fin(acc[mf][nf][r] + bb));
        }
      }
    __syncthreads();
    const int vl = tid >> 1, part = tid & 1;
    const int bI = row0 >> 11;
    u16* dst = Vt + (size_t)(bI * 512 + col0 + vl) * 2048 + (row0 & 2047) + part * 64;
    const u16* sp = &Tr[vl * 128 + part * 64];
#pragma unroll
    for (int q = 0; q < 8; ++q)
      *(uint4*)(dst + q * 8) = *(const uint4*)(sp + q * 8);
  }
}

// ---------------- K2: column denominators ----------------
// 256 equal blocks (1-D, b = id&7 -> XCD-pinned): pair (px, 63-px) of 32-i
// tiles sequentially.  8 waves = (ih) x (jq).  K rows in regs, Q staged via
// glds double-buffer.  Column sums accumulate in regs; direct store.
__global__ __launch_bounds__(512, 2) void denom_mfma(
    const u16* __restrict__ Qs, const u16* __restrict__ Kw, float* __restrict__ rdn) {
  __shared__ __align__(16) u16 QB[2][32768];  // [64 j][512 c] swizzled
  __shared__ float red[2][4][16];
  const int id = blockIdx.x;
  const int b = id & 7, px = id >> 3;
  const int tid = threadIdx.x, lane = tid & 63, w = tid >> 6;
  const int lrow = lane & 15, lg = lane >> 4;
  const int ih = w >> 2, jq = w & 3;
  const size_t kbase = (size_t)b * 2048 * 512;
  const f32x4 Z4 = {0.f, 0.f, 0.f, 0.f};

  for (int half = 0; half < 2; ++half) {
    const int it = half ? (63 - px) : px;
    const int i0 = it * 32;
    bf16x8 Kf[16];
    const u16* kr = Kw + kbase + (size_t)(i0 + ih * 16 + lrow) * 512;
#pragma unroll
    for (int cs = 0; cs < 16; ++cs) Kf[cs] = *(const bf16x8*)(kr + cs * 32 + lg * 8);
    float dacc[4] = {0.f, 0.f, 0.f, 0.f};
    const int jstart = i0 & ~63;
    const int NW = (2048 - jstart) >> 6;
#pragma unroll
    for (int p = 0; p < 8; ++p) {
      const int row = p * 8 + w;
      glds16(Qs + (size_t)(b * 2048 + jstart + row) * 2048 + ((lane ^ (row & 7)) << 3),
             &QB[0][row * 512]);
    }
    for (int win = 0; win < NW; ++win) {
      const int cur = win & 1;
      const int j0w = jstart + win * 64;
      if (win + 1 < NW) {
#pragma unroll
        for (int p = 0; p < 8; ++p) {
          const int row = p * 8 + w;
          glds16(Qs + (size_t)(b * 2048 + j0w + 64 + row) * 2048 + ((lane ^ (row & 7)) << 3),
                 &QB[cur ^ 1][row * 512]);
        }
        asm volatile("s_waitcnt vmcnt(8)" ::: "memory");
      } else {
        asm volatile("s_waitcnt vmcnt(0)" ::: "memory");
      }
      __builtin_amdgcn_s_barrier();
      const u16* qb = &QB[cur][0];
      const int qrow = jq * 16 + lrow;
      f32x4 sA = Z4, sB = Z4;
#pragma unroll
      for (int cs = 0; cs < 8; ++cs) {
        bf16x8 q0 = *(const bf16x8*)(qb + qrow * 512 + (((cs * 4 + lg) ^ (qrow & 7)) << 3));
        bf16x8 q1 = *(const bf16x8*)(qb + qrow * 512 + ((((cs + 8) * 4 + lg) ^ (qrow & 7)) << 3));
        sA = MFMA16(Kf[cs], q0, sA);
        sB = MFMA16(Kf[cs + 8], q1, sB);
      }
      const int jG = j0w + jq * 16 + lrow;
      const int ib = i0 + ih * 16 + lg * 4;
#pragma unroll
      for (int r = 0; r < 4; ++r) {
        float e = (jG >= ib + r) ? expclamp((sA[r] + sB[r]) * SCALE) : 0.f;
        e += __shfl_xor(e, 1); e += __shfl_xor(e, 2);
        e += __shfl_xor(e, 4); e += __shfl_xor(e, 8);
        dacc[r] += e;
      }
      asm volatile("s_waitcnt lgkmcnt(0)" ::: "memory");
      __builtin_amdgcn_s_barrier();
    }
    if (lrow == 0) {
#pragma unroll
      for (int r = 0; r < 4; ++r) red[ih][jq][lg * 4 + r] = dacc[r];
    }
    __syncthreads();
    if (tid < 32) {
      const int ihh = tid >> 4, il = tid & 15;
      const float d = red[ihh][0][il] + red[ihh][1][il] + red[ihh][2][il] + red[ihh][3][il];
      rdn[(size_t)(b * 2048 + i0 + ihh * 16 + il) * 1024 + 256] = d;
    }
    __syncthreads();
  }
}

// ---------------- K3: fused causal read ----------------
// 256 equal blocks (1-D, b = id&7 -> XCD-pinned; K[b]+Vt[b] = 4 MB L2-resident):
// pair (px, 63-px) of 32-j tiles sequentially.  8 waves: (jh, iq/vq).  Q in
// regs; K glds dbuf + counted vmcnt; V prefetched to regs at window top (T14);
// P through LDS.
__global__ __launch_bounds__(512, 2) void read_mfma(
    const u16* __restrict__ Qs, const u16* __restrict__ Kw, const u16* __restrict__ Vt,
    const float* __restrict__ rdn, float* __restrict__ outf) {
  __shared__ __align__(16) u16 KB[2][32768];  // [64 i][512 c] swizzled
  __shared__ __align__(16) u16 PB[32 * 72];   // P[32 j][64 i], stride 72
  const int id = blockIdx.x;
  const int b = id & 7, px = id >> 3;
  const int tid = threadIdx.x, lane = tid & 63, w = tid >> 6;
  const int lrow = lane & 15, lg = lane >> 4;
  const int jh = w >> 2, q4 = w & 3;
  const size_t kbase = (size_t)b * 2048 * 512;
  const size_t vbase = (size_t)b * 512 * 2048;
  const f32x4 Z4 = {0.f, 0.f, 0.f, 0.f};

  for (int half = 0; half < 2; ++half) {
    const int jt = half ? (63 - px) : px;
    const int j0 = jt * 32;
    const int NW = (jt + 2) >> 1;  // ceil((jt+1)/2) windows of 64 i

    bf16x8 Qf[16];
    const u16* qr = Qs + (size_t)(b * 2048 + j0 + jh * 16 + lrow) * 2048;
#pragma unroll
    for (int cs = 0; cs < 16; ++cs) Qf[cs] = *(const bf16x8*)(qr + cs * 32 + lg * 8);
    f32x4 O[8];
#pragma unroll
    for (int t = 0; t < 8; ++t) O[t] = Z4;

#pragma unroll
    for (int p = 0; p < 8; ++p) {
      const int row = p * 8 + w;
      glds16(Kw + kbase + (size_t)row * 512 + ((lane ^ (row & 7)) << 3),
             &KB[0][row * 512]);
    }

    for (int win = 0; win < NW; ++win) {
      const int cur = win & 1;
      const int i0 = win * 64;
      bf16x8 Vp[16];
#pragma unroll
      for (int t = 0; t < 8; ++t)
#pragma unroll
        for (int is = 0; is < 2; ++is)
          Vp[t * 2 + is] = *(const bf16x8*)(
              Vt + vbase + (size_t)(q4 * 128 + t * 16 + lrow) * 2048 + i0 + is * 32 + lg * 8);
      const float dsum = rdn[(size_t)(b * 2048 + i0 + q4 * 16 + lrow) * 1024 + 256];
      if (win + 1 < NW) {
        const int ni = i0 + 64;
#pragma unroll
        for (int p = 0; p < 8; ++p) {
          const int row = p * 8 + w;
          glds16(Kw + kbase + (size_t)(ni + row) * 512 + ((lane ^ (row & 7)) << 3),
                 &KB[cur ^ 1][row * 512]);
        }
        asm volatile("s_waitcnt vmcnt(25)" ::: "memory");
      } else {
        asm volatile("s_waitcnt vmcnt(17)" ::: "memory");
      }
      __builtin_amdgcn_s_barrier();

      const u16* kb = &KB[cur][0];
      const int krow = q4 * 16 + lrow;
      f32x4 sA = Z4, sB = Z4;
#pragma unroll
      for (int cs = 0; cs < 8; ++cs) {
        bf16x8 k0 = *(const bf16x8*)(kb + krow * 512 + (((cs * 4 + lg) ^ (krow & 7)) << 3));
        bf16x8 k1 = *(const bf16x8*)(kb + krow * 512 + ((((cs + 8) * 4 + lg) ^ (krow & 7)) << 3));
        sA = MFMA16(Qf[cs], k0, sA);
        sB = MFMA16(Qf[cs + 8], k1, sB);
      }
      if (win + 1 < NW) asm volatile("s_waitcnt vmcnt(8)" ::: "memory");
      else              asm volatile("s_waitcnt vmcnt(0)" ::: "memory");
      const float rd = 1.0f / fmaxf(dsum, 1e-30f);
      const int iG = i0 + q4 * 16 + lrow;
      const int jb = j0 + jh * 16 + lg * 4;
#pragma unroll
      for (int r = 0; r < 4; ++r) {
        const float e = (iG <= jb + r) ? expclamp((sA[r] + sB[r]) * SCALE) * rd : 0.f;
        PB[(jh * 16 + lg * 4 + r) * 72 + q4 * 16 + lrow] = f2b(e);
      }
      asm volatile("s_waitcnt lgkmcnt(0)" ::: "memory");
      __builtin_amdgcn_s_barrier();

      const bf16x8 pa0 = *(const bf16x8*)&PB[(jh * 16 + lrow) * 72 + lg * 8];
      const bf16x8 pa1 = *(const bf16x8*)&PB[(jh * 16 + lrow) * 72 + 32 + lg * 8];
#pragma unroll
      for (int t = 0; t < 8; ++t) {
        O[t] = MFMA16(pa0, Vp[t * 2 + 0], O[t]);
        O[t] = MFMA16(pa1, Vp[t * 2 + 1], O[t]);
      }
    }

#pragma unroll
    for (int t = 0; t < 8; ++t) {
      const int v = q4 * 128 + t * 16 + lrow;
#pragma unroll
      for (int r = 0; r < 4; ++r) {
        const int jj = j0 + jh * 16 + lg * 4 + r;
        outf[(size_t)(b * 2048 + jj) * 1024 + 512 + v] = fin(O[t][r]);
      }
    }
    __syncthreads();
  }
}

// ---------------- K4: passthrough fp32 X -> out[:,0:512] (LAST) ----------------
__global__ __launch_bounds__(256) void copy_in_kernel(
    const float* __restrict__ X, float* __restrict__ outf) {
  size_t idx = (size_t)blockIdx.x * 256 + threadIdx.x;
  size_t row = idx >> 7;
  int c = (int)(idx & 127) * 4;
  *(float4*)&outf[row * 1024 + c] = *(const float4*)&X[row * 512 + c];
}

extern "C" void kernel_launch(void* const* d_in, const int* in_sizes, int n_in,
                              void* d_out, int out_size, void* d_ws, size_t ws_size,
                              hipStream_t stream) {
  const float* X  = (const float*)d_in[0];
  const float* Wq = (const float*)d_in[1];
  const float* bq = (const float*)d_in[2];
  const float* Wk = (const float*)d_in[3];
  const float* bk = (const float*)d_in[4];
  const float* Wv = (const float*)d_in[5];
  const float* bv = (const float*)d_in[6];

  char* ws = (char*)d_ws;
  const size_t SZ = (size_t)16384 * 512 * sizeof(u16);
  u16* Kw = (u16*)(ws);
  u16* Vt = (u16*)(ws + SZ);

  qkv_mfma<<<dim3(1536), 256, 0, stream>>>(X, Wq, bq, Wk, bk, Wv, bv,
                                           (u16*)d_out, Kw, Vt);
  denom_mfma<<<dim3(256), 512, 0, stream>>>((const u16*)d_out, Kw, (float*)d_out);
  read_mfma<<<dim3(256), 512, 0, stream>>>((const u16*)d_out, Kw, Vt,
                                           (const float*)d_out, (float*)d_out);
  copy_in_kernel<<<8192, 256, 0, stream>>>(X, (float*)d_out);
}

// Round 5
// 381.383 us; speedup vs baseline: 1.5658x; 1.1874x over previous
//
#include <hip/hip_runtime.h>

typedef unsigned short u16;
using bf16x8 = __attribute__((ext_vector_type(8))) short;
using f32x4  = __attribute__((ext_vector_type(4))) float;

static __device__ __forceinline__ u16 f2b(float f) {
  unsigned int x = __builtin_bit_cast(unsigned int, f);
  unsigned int r = (x + 0x7fffu + ((x >> 16) & 1u)) >> 16;
  return (u16)r;
}
static __device__ __forceinline__ float fin(float x) { return (x != x) ? 0.f : x; }
static __device__ __forceinline__ float expclamp(float x) {
  return __expf(fminf(fmaxf(x, -80.f), 80.f));
}
// packed f32->bf16 RNE convert (same rounding as f2b)
static __device__ __forceinline__ unsigned cvt2(float lo, float hi) {
  unsigned r;
  asm("v_cvt_pk_bf16_f32 %0, %1, %2" : "=v"(r) : "v"(lo), "v"(hi));
  return r;
}

#define SCALE 0.04419417382415922f  // 1/sqrt(512)
#define MFMA16(a, b, c) __builtin_amdgcn_mfma_f32_16x16x32_bf16((a), (b), (c), 0, 0, 0)

static __device__ __forceinline__ void glds16(const u16* g, u16* l) {
  __builtin_amdgcn_global_load_lds(
      (const __attribute__((address_space(1))) unsigned int*)(unsigned long long)(const void*)g,
      (__attribute__((address_space(3))) unsigned int*)(unsigned int)(unsigned long long)(void*)l,
      16, 0, 0);
}

// Memory plan (ws = 33,554,432 B exactly):
//   ws: K bf16 [8][2048][512] @0; Vt bf16 [8][512][2048] (V transposed) @16.78MB
//   d_out per fp32-row r (4096 B): [0,1024) Q bf16 stash (stride 2048 u16),
//   [1024,1040) denom partials f32 x4 (slots 256..259) for column i=r%2048,
//   [2048,4096) read output.  copy_in (LAST) overwrites [0,2048).
//
// XCD placement (T1, verified R4): b = blockIdx.x & 7 pins each batch to one
// XCD; K[b]+Vt[b] (4 MB) / Q[b] (2 MB) stay L2-resident.

// ---------------- K1: QKV projection, MFMA GEMM (unchanged, verified) ----------------
__global__ __launch_bounds__(256) void qkv_mfma(
    const float* __restrict__ X,
    const float* __restrict__ Wq, const float* __restrict__ bq,
    const float* __restrict__ Wk, const float* __restrict__ bk,
    const float* __restrict__ Wv, const float* __restrict__ bv,
    u16* __restrict__ outq, u16* __restrict__ Kw, u16* __restrict__ Vt) {
  __shared__ __align__(16) u16 SM[16384];
  u16* As = SM;
  u16* Bs = SM + 8192;
  const int id = blockIdx.x;
  const int xcd = id & 7;
  const int slot = id >> 3;
  const int bxl = slot / 12;
  const int byz = slot - bxl * 12;
  const int z = byz >> 2;
  const int by = byz & 3;
  const int bx = (xcd << 4) + bxl;
  const float* W = (z == 0) ? Wq : ((z == 1) ? Wk : Wv);
  const float* bias = (z == 0) ? bq : ((z == 1) ? bk : bv);
  const int row0 = bx * 128;
  const int col0 = by * 128;
  const int tid = threadIdx.x, lane = tid & 63, w = tid >> 6;
  const int lrow = lane & 15, lg = lane >> 4;
  const int qm = w >> 1, qn = w & 1;
  const int srow = tid >> 1, sh = tid & 1;

  const f32x4 Z4 = {0.f, 0.f, 0.f, 0.f};
  f32x4 acc[4][4];
#pragma unroll
  for (int m = 0; m < 4; ++m)
#pragma unroll
    for (int n = 0; n < 4; ++n) acc[m][n] = Z4;

  const float* Xr = X + (size_t)(row0 + srow) * 512;
  const float* Wr = W + (size_t)(col0 + srow) * 512;

  for (int ks = 0; ks < 8; ++ks) {
    const int k0 = ks * 64;
    __syncthreads();
#pragma unroll
    for (int s4 = 0; s4 < 4; ++s4) {
      const int slt = sh * 4 + s4;
      const int ds = ((slt ^ (srow & 7)) << 3);
      {
        float4 f0 = *(const float4*)(Xr + k0 + slt * 8);
        float4 f1 = *(const float4*)(Xr + k0 + slt * 8 + 4);
        uint4 pk;
        pk.x = cvt2(f0.x, f0.y); pk.y = cvt2(f0.z, f0.w);
        pk.z = cvt2(f1.x, f1.y); pk.w = cvt2(f1.z, f1.w);
        *(uint4*)&As[srow * 64 + ds] = pk;
      }
      {
        float4 f0 = *(const float4*)(Wr + k0 + slt * 8);
        float4 f1 = *(const float4*)(Wr + k0 + slt * 8 + 4);
        uint4 pk;
        pk.x = cvt2(f0.x, f0.y); pk.y = cvt2(f0.z, f0.w);
        pk.z = cvt2(f1.x, f1.y); pk.w = cvt2(f1.z, f1.w);
        *(uint4*)&Bs[srow * 64 + ds] = pk;
      }
    }
    __syncthreads();
#pragma unroll
    for (int cs = 0; cs < 2; ++cs) {
      bf16x8 af[4], bfr[4];
#pragma unroll
      for (int mf = 0; mf < 4; ++mf) {
        const int r = qm * 64 + mf * 16 + lrow;
        af[mf] = *(const bf16x8*)&As[r * 64 + (((cs * 4 + lg) ^ (r & 7)) << 3)];
      }
#pragma unroll
      for (int nf = 0; nf < 4; ++nf) {
        const int r = qn * 64 + nf * 16 + lrow;
        bfr[nf] = *(const bf16x8*)&Bs[r * 64 + (((cs * 4 + lg) ^ (r & 7)) << 3)];
      }
#pragma unroll
      for (int mf = 0; mf < 4; ++mf)
#pragma unroll
        for (int nf = 0; nf < 4; ++nf)
          acc[mf][nf] = MFMA16(af[mf], bfr[nf], acc[mf][nf]);
    }
  }

  if (z < 2) {
    u16* O = (z == 0) ? outq : Kw;
    const int ldo = (z == 0) ? 2048 : 512;
#pragma unroll
    for (int mf = 0; mf < 4; ++mf)
#pragma unroll
      for (int nf = 0; nf < 4; ++nf) {
        const int C = col0 + qn * 64 + nf * 16 + lrow;
        const float bb = bias[C];
#pragma unroll
        for (int r = 0; r < 4; ++r) {
          const int R = row0 + qm * 64 + mf * 16 + lg * 4 + r;
          O[(size_t)R * ldo + C] = f2b(fin(acc[mf][nf][r] + bb));
        }
      }
  } else {
    __syncthreads();
    u16* Tr = SM;  // [128][128]
#pragma unroll
    for (int mf = 0; mf < 4; ++mf)
#pragma unroll
      for (int nf = 0; nf < 4; ++nf) {
        const int vl = qn * 64 + nf * 16 + lrow;
        const float bb = bias[col0 + vl];
#pragma unroll
        for (int r = 0; r < 4; ++r) {
          const int tl = qm * 64 + mf * 16 + lg * 4 + r;
          Tr[vl * 128 + tl] = f2b(fin(acc[mf][nf][r] + bb));
        }
      }
    __syncthreads();
    const int vl = tid >> 1, part = tid & 1;
    const int bI = row0 >> 11;
    u16* dst = Vt + (size_t)(bI * 512 + col0 + vl) * 2048 + (row0 & 2047) + part * 64;
    const u16* sp = &Tr[vl * 128 + part * 64];
#pragma unroll
    for (int q = 0; q < 8; ++q)
      *(uint4*)(dst + q * 8) = *(const uint4*)(sp + q * 8);
  }
}

// ---------------- K2: column denominator partials ----------------
// Grid 512: b = id&7 (XCD pin); rest: py (16 i-tile-pairs of 64 i), stripe (4).
// Two passes: tile py then 31-py.  8 waves = (4 ihh x 2 jq); 64 K-rows in regs
// (16/wave).  j-sweep in 32-j windows, stripe s takes windows m = m0+s, +4...
// Q staged via glds dbuf; one __syncthreads per window (drains glds).
// Writes RAW partial to slot 256+stripe; read_mfma sums the float4.
__global__ __launch_bounds__(512, 4) void denom_mfma(
    const u16* __restrict__ Qs, const u16* __restrict__ Kw, float* __restrict__ rdn) {
  __shared__ __align__(16) u16 QB[2][16384];  // [32 j][512 c] swizzled
  __shared__ float red[4][2][16];
  const int id = blockIdx.x;
  const int b = id & 7, rest = id >> 3;
  const int py = rest >> 2, stripe = rest & 3;
  const int tid = threadIdx.x, lane = tid & 63, w = tid >> 6;
  const int lrow = lane & 15, lg = lane >> 4;
  const int ihh = w >> 1, jq = w & 1;
  const size_t kbase = (size_t)b * 2048 * 512;
  const f32x4 Z4 = {0.f, 0.f, 0.f, 0.f};

  for (int pass = 0; pass < 2; ++pass) {
    const int ti = pass ? (31 - py) : py;
    const int i0 = ti * 64;
    bf16x8 Kf[16];
    const u16* kr = Kw + kbase + (size_t)(i0 + ihh * 16 + lrow) * 512;
#pragma unroll
    for (int cs = 0; cs < 16; ++cs) Kf[cs] = *(const bf16x8*)(kr + cs * 32 + lg * 8);
    float dacc[4] = {0.f, 0.f, 0.f, 0.f};
    const int m0 = (i0 >> 5) + stripe;  // first 32-j window for this stripe

    if (m0 <= 63) {
#pragma unroll
      for (int p = 0; p < 4; ++p) {  // stage window m0: 32 rows / 8 waves
        const int row = p * 8 + w;
        glds16(Qs + (size_t)(b * 2048 + m0 * 32 + row) * 2048 + ((lane ^ (row & 7)) << 3),
               &QB[0][row * 512]);
      }
    }
    __syncthreads();

    int n = 0;
    for (int m = m0; m <= 63; m += 4, ++n) {
      const int cur = n & 1;
      if (m + 4 <= 63) {
#pragma unroll
        for (int p = 0; p < 4; ++p) {
          const int row = p * 8 + w;
          glds16(Qs + (size_t)(b * 2048 + (m + 4) * 32 + row) * 2048 + ((lane ^ (row & 7)) << 3),
                 &QB[cur ^ 1][row * 512]);
        }
      }
      const u16* qb = &QB[cur][0];
      const int qrow = jq * 16 + lrow;
      f32x4 sA = Z4, sB = Z4;
#pragma unroll
      for (int cs = 0; cs < 8; ++cs) {
        bf16x8 q0 = *(const bf16x8*)(qb + qrow * 512 + (((cs * 4 + lg) ^ (lrow & 7)) << 3));
        bf16x8 q1 = *(const bf16x8*)(qb + qrow * 512 + (((32 + cs * 4 + lg) ^ (lrow & 7)) << 3));
        sA = MFMA16(Kf[cs], q0, sA);
        sB = MFMA16(Kf[cs + 8], q1, sB);
      }
      const int jG = m * 32 + jq * 16 + lrow;
      const int ib = i0 + ihh * 16 + lg * 4;
#pragma unroll
      for (int r = 0; r < 4; ++r) {
        float e = (jG >= ib + r) ? expclamp((sA[r] + sB[r]) * SCALE) : 0.f;
        e += __shfl_xor(e, 1); e += __shfl_xor(e, 2);
        e += __shfl_xor(e, 4); e += __shfl_xor(e, 8);
        dacc[r] += e;
      }
      __syncthreads();  // drains this window's glds; publishes nothing else
    }

    if (lrow == 0) {
#pragma unroll
      for (int r = 0; r < 4; ++r) red[ihh][jq][lg * 4 + r] = dacc[r];
    }
    __syncthreads();
    if (tid < 64) {
      const float d = red[tid >> 4][0][tid & 15] + red[tid >> 4][1][tid & 15];
      rdn[(size_t)(b * 2048 + i0 + tid) * 1024 + 256 + stripe] = d;
    }
    __syncthreads();
  }
}

// ---------------- K3: fused causal read, producer/consumer waves ----------------
// Grid 512: b = id&7 (XCD pin); s = id>>3: jt = s<32 ? s : 95-s  (CU's two
// blocks sum to constant work).  JB=32 j, IW=32 i.  8 waves: role 0 (4 waves,
// 2jh x 2iq) = QK+exp -> PB[cur]; role 1 (4 waves, vq each owning 128 v) =
// P[prev] x V -> O.  V read once per window.  K via glds dbuf.  One
// __syncthreads per window (its vmcnt(0) drain covers the glds).  Qf and O
// share RS[16] (bit-cast union) to stay <=128 VGPR -> 2 blocks/CU, 4 waves/SIMD.
__global__ __launch_bounds__(512, 4) void read_mfma(
    const u16* __restrict__ Qs, const u16* __restrict__ Kw, const u16* __restrict__ Vt,
    const float* __restrict__ rdn, float* __restrict__ outf) {
  __shared__ __align__(16) u16 KB[2][16384];  // [32 i][512 c] swizzled
  __shared__ __align__(16) u16 PB[2][32 * 40];  // P[32 j][32 i], stride 40
  const int id = blockIdx.x;
  const int b = id & 7, s = id >> 3;
  const int jt = (s < 32) ? s : 95 - s;
  const int j0 = jt * 32;
  const int tid = threadIdx.x, lane = tid & 63, w = tid >> 6;
  const int lrow = lane & 15, lg = lane >> 4;
  const int role = w >> 2, wq = w & 3;
  const int jh = wq >> 1, iq = wq & 1;  // QK decomposition
  const int vq = wq;                     // PV decomposition
  const int NW = jt + 1;
  const size_t kbase = (size_t)b * 2048 * 512;
  const size_t vbase = (size_t)b * 512 * 2048;
  const f32x4 Z4 = {0.f, 0.f, 0.f, 0.f};

  // RS union: QK waves keep Q fragments (bit-cast bf16x8); PV waves keep O.
  f32x4 RS[16];
  if (role == 0) {
    const u16* qr = Qs + (size_t)(b * 2048 + j0 + jh * 16 + lrow) * 2048;
#pragma unroll
    for (int cs = 0; cs < 16; ++cs)
      RS[cs] = __builtin_bit_cast(f32x4, *(const bf16x8*)(qr + cs * 32 + lg * 8));
  } else {
#pragma unroll
    for (int t = 0; t < 16; ++t) RS[t] = Z4;
  }

#pragma unroll
  for (int p = 0; p < 4; ++p) {  // prologue: stage window 0
    const int row = p * 8 + w;
    glds16(Kw + kbase + (size_t)row * 512 + ((lane ^ (row & 7)) << 3),
           &KB[0][row * 512]);
  }
  __syncthreads();

  for (int t = 0; t <= NW; ++t) {
    if (t + 1 < NW) {
#pragma unroll
      for (int p = 0; p < 4; ++p) {
        const int row = p * 8 + w;
        glds16(Kw + kbase + (size_t)((t + 1) * 32 + row) * 512 + ((lane ^ (row & 7)) << 3),
               &KB[(t + 1) & 1][row * 512]);
      }
    }
    if (role == 0) {
      if (t < NW) {
        const int i0 = t * 32;
        const int iG = i0 + iq * 16 + lrow;
        const float4 rp = *(const float4*)&rdn[(size_t)(b * 2048 + iG) * 1024 + 256];
        const u16* kb = &KB[t & 1][0];
        const int krow = iq * 16 + lrow;
        f32x4 sA = Z4, sB = Z4;
#pragma unroll
        for (int cs = 0; cs < 8; ++cs) {
          bf16x8 k0 = *(const bf16x8*)(kb + krow * 512 + (((cs * 4 + lg) ^ (lrow & 7)) << 3));
          bf16x8 k1 = *(const bf16x8*)(kb + krow * 512 + (((32 + cs * 4 + lg) ^ (lrow & 7)) << 3));
          sA = MFMA16(__builtin_bit_cast(bf16x8, RS[cs]), k0, sA);
          sB = MFMA16(__builtin_bit_cast(bf16x8, RS[cs + 8]), k1, sB);
        }
        const float rd = 1.0f / fmaxf(rp.x + rp.y + rp.z + rp.w, 1e-30f);
        const int jb = j0 + jh * 16 + lg * 4;
#pragma unroll
        for (int r = 0; r < 4; ++r) {
          const float e = (iG <= jb + r) ? expclamp((sA[r] + sB[r]) * SCALE) * rd : 0.f;
          PB[t & 1][(jh * 16 + lg * 4 + r) * 40 + iq * 16 + lrow] = f2b(e);
        }
      }
    } else {
      if (t >= 1) {
        const int i0 = (t - 1) * 32;
        bf16x8 Vp[8];
#pragma unroll
        for (int vt = 0; vt < 8; ++vt)
          Vp[vt] = *(const bf16x8*)(
              Vt + vbase + (size_t)(vq * 128 + vt * 16 + lrow) * 2048 + i0 + lg * 8);
        const u16* pb = &PB[(t - 1) & 1][0];
        const bf16x8 pa0 = *(const bf16x8*)(pb + lrow * 40 + lg * 8);
        const bf16x8 pa1 = *(const bf16x8*)(pb + (16 + lrow) * 40 + lg * 8);
#pragma unroll
        for (int vt = 0; vt < 8; ++vt) {
          RS[vt] = MFMA16(pa0, Vp[vt], RS[vt]);          // j 0..15
          RS[8 + vt] = MFMA16(pa1, Vp[vt], RS[8 + vt]);  // j 16..31
        }
      }
    }
    __syncthreads();  // publishes PB[t&1]; drains this iter's K-glds
  }

  if (role == 1) {
#pragma unroll
    for (int jh2 = 0; jh2 < 2; ++jh2)
#pragma unroll
      for (int vt = 0; vt < 8; ++vt) {
        const int v = vq * 128 + vt * 16 + lrow;
        const f32x4 o = RS[jh2 * 8 + vt];
#pragma unroll
        for (int r = 0; r < 4; ++r) {
          const int jj = j0 + jh2 * 16 + lg * 4 + r;
          outf[(size_t)(b * 2048 + jj) * 1024 + 512 + v] = fin(o[r]);
        }
      }
  }
}

// ---------------- K4: passthrough fp32 X -> out[:,0:512] (LAST) ----------------
__global__ __launch_bounds__(256) void copy_in_kernel(
    const float* __restrict__ X, float* __restrict__ outf) {
  size_t idx = (size_t)blockIdx.x * 256 + threadIdx.x;
  size_t row = idx >> 7;
  int c = (int)(idx & 127) * 4;
  *(float4*)&outf[row * 1024 + c] = *(const float4*)&X[row * 512 + c];
}

extern "C" void kernel_launch(void* const* d_in, const int* in_sizes, int n_in,
                              void* d_out, int out_size, void* d_ws, size_t ws_size,
                              hipStream_t stream) {
  const float* X  = (const float*)d_in[0];
  const float* Wq = (const float*)d_in[1];
  const float* bq = (const float*)d_in[2];
  const float* Wk = (const float*)d_in[3];
  const float* bk = (const float*)d_in[4];
  const float* Wv = (const float*)d_in[5];
  const float* bv = (const float*)d_in[6];

  char* ws = (char*)d_ws;
  const size_t SZ = (size_t)16384 * 512 * sizeof(u16);
  u16* Kw = (u16*)(ws);
  u16* Vt = (u16*)(ws + SZ);

  qkv_mfma<<<dim3(1536), 256, 0, stream>>>(X, Wq, bq, Wk, bk, Wv, bv,
                                           (u16*)d_out, Kw, Vt);
  denom_mfma<<<dim3(512), 512, 0, stream>>>((const u16*)d_out, Kw, (float*)d_out);
  read_mfma<<<dim3(512), 512, 0, stream>>>((const u16*)d_out, Kw, Vt,
                                           (const float*)d_out, (float*)d_out);
  copy_in_kernel<<<8192, 256, 0, stream>>>(X, (float*)d_out);
}